// Round 6
// baseline (742.824 us; speedup 1.0000x reference)
//
#include <hip/hip_runtime.h>
#include <math.h>

typedef long long i64;
typedef unsigned long long u64;

#define GWD 1024
#define GMSK 1023
#define GSH 10
#define NBE 1024   // kE2 grid

__device__ __forceinline__ int deg_of(int m) {
  int xx = m & GMSK, yy = m >> GSH;
  return (xx > 0) + (xx < GMSK) + (yy > 0) + (yy < GMSK);
}

// ============ A: level-1 matching, fully static neighbor slots ============
__global__ __launch_bounds__(256)
void kA_match1(const float* __restrict__ x, int* __restrict__ partner1, int n) {
#pragma clang fp contract(off)
  int m = blockIdx.x * 256 + threadIdx.x;
  if (m >= n) return;
  int xx = m & GMSK, yy = m >> GSH;
  bool vW = xx > 0, vE = xx < GMSK, vN = yy > 0, vS = yy < GMSK;
  int cnt = (int)vW + (int)vE + (int)vN + (int)vS;
  float invi = 1.0f / (float)cnt;
  float xm0 = x[(i64)m * 5];
  float best = -INFINITY;
  int pr = n;
#define NB1(valid, J)                                                  \
  if (valid) {                                                         \
    int j = (J);                                                       \
    float a0 = x[(i64)j * 5];                                          \
    float w = fabsf(xm0 - a0) * (invi + 1.0f / (float)deg_of(j));      \
    if (w > best) { best = w; pr = j; }                                \
  }
  NB1(vN, m - GWD)
  NB1(vW, m - 1)
  NB1(vE, m + 1)
  NB1(vS, m + GWD)
#undef NB1
  partner1[m] = pr;
}

// ============ B: c1, pooled features (replicated), centroids (replicated) ============
__device__ __forceinline__ void conv1_static(const float* __restrict__ x, int m,
                                             const float* w1, const float* w1r,
                                             const float* b1, float (&out)[16]) {
  int xx = m & GMSK, yy = m >> GSH;
  bool vW = xx > 0, vE = xx < GMSK, vN = yy > 0, vS = yy < GMSK;
  int cnt = (int)vW + (int)vE + (int)vN + (int)vS;
  float s0 = 0.f, s1 = 0.f, s2 = 0.f, s3 = 0.f, s4 = 0.f;
#define ACC1(valid, J)                                     \
  if (valid) {                                             \
    const float* xj = x + (i64)(J) * 5;                    \
    s0 += xj[0]; s1 += xj[1]; s2 += xj[2];                 \
    s3 += xj[3]; s4 += xj[4];                              \
  }
  ACC1(vN, m - GWD)
  ACC1(vW, m - 1)
  ACC1(vE, m + 1)
  ACC1(vS, m + GWD)
#undef ACC1
  const float* xm = x + (i64)m * 5;
  float m0 = xm[0], m1 = xm[1], m2 = xm[2], m3 = xm[3], m4 = xm[4];
  float cf = (float)cnt;
#pragma unroll
  for (int f = 0; f < 16; ++f) {
    float a  = s0 * w1[f] + s1 * w1[16 + f] + s2 * w1[32 + f] + s3 * w1[48 + f] + s4 * w1[64 + f];
    float rt = m0 * w1r[f] + m1 * w1r[16 + f] + m2 * w1r[32 + f] + m3 * w1r[48 + f] + m4 * w1r[64 + f];
    out[f] = fmaxf(a / cf + rt + b1[f], 0.0f);
  }
}

__global__ __launch_bounds__(256)
void kB_pool1(const float* __restrict__ x, const float* __restrict__ pos,
              const int* __restrict__ partner1,
              const float* __restrict__ W1, const float* __restrict__ W1r,
              const float* __restrict__ b1,
              int* __restrict__ c1, float* __restrict__ xpf,
              float* __restrict__ pospf, int n) {
#pragma clang fp contract(off)
  __shared__ float w1s[80], w1rs[80], b1s[16];
  for (int t = threadIdx.x; t < 80; t += 256) { w1s[t] = W1[t]; w1rs[t] = W1r[t]; }
  if (threadIdx.x < 16) b1s[threadIdx.x] = b1[threadIdx.x];
  __syncthreads();
  int m = blockIdx.x * 256 + threadIdx.x;
  if (m >= n) return;
  int p = partner1[m];
  bool mut = (partner1[p] == m);
  c1[m] = mut ? min(m, p) : m;

  float px = pos[(i64)m * 2], py = pos[(i64)m * 2 + 1];
  if (mut) {
    px = (px + pos[(i64)p * 2]) * 0.5f;
    py = (py + pos[(i64)p * 2 + 1]) * 0.5f;
  }
  pospf[(i64)m * 2] = px;
  pospf[(i64)m * 2 + 1] = py;

  float v[16];
  conv1_static(x, m, w1s, w1rs, b1s, v);
  if (mut) {
    float u[16];
    conv1_static(x, p, w1s, w1rs, b1s, u);
#pragma unroll
    for (int f = 0; f < 16; ++f) v[f] = fmaxf(v[f], u[f]);
  }
#pragma unroll
  for (int f = 0; f < 16; ++f) xpf[(i64)m * 16 + f] = v[f];
}

// ============ C: coarse degree (replicated per node) ============
__device__ __forceinline__ int dcount(const int* __restrict__ c1, int q, int cq) {
  int xx = q & GMSK, yy = q >> GSH;
  int d = 0;
  if (yy > 0    && c1[q - GWD] != cq) ++d;
  if (xx > 0    && c1[q - 1]   != cq) ++d;
  if (xx < GMSK && c1[q + 1]   != cq) ++d;
  if (yy < GMSK && c1[q + GWD] != cq) ++d;
  return d;
}

__global__ __launch_bounds__(256)
void kC_deg2(const int* __restrict__ partner1, const int* __restrict__ c1,
             int* __restrict__ deg2f, int n) {
  int m = blockIdx.x * 256 + threadIdx.x;
  if (m >= n) return;
  int cm = c1[m];
  int p = partner1[m];
  bool mut = (partner1[p] == m);
  int d = dcount(c1, m, cm);
  if (mut) d += dcount(c1, p, cm);
  deg2f[m] = d;
}

// ============ D: level-2 matching (heads only), static 8 slots ============
__global__ __launch_bounds__(256)
void kD_match2(const int* __restrict__ partner1, const int* __restrict__ c1,
               const float* __restrict__ pospf, const int* __restrict__ deg2f,
               int* __restrict__ partner2, int n) {
#pragma clang fp contract(off)
  int i = blockIdx.x * 256 + threadIdx.x;
  if (i >= n) return;
  if (c1[i] != i) return;  // heads only
  int p = partner1[i];
  bool mut = (partner1[p] == i);
  float pix = pospf[(i64)i * 2], piy = pospf[(i64)i * 2 + 1];
  int di = deg2f[i];
  float invi = (di > 0) ? 1.0f / (float)di : 0.0f;
  float best = -INFINITY;
  int bc = n;
#define NB2(valid, J)                                                   \
  if (valid) {                                                          \
    int j = (J);                                                        \
    int cu = c1[j];                                                     \
    if (cu != i) {                                                      \
      float dx = pix - pospf[(i64)j * 2];                               \
      float dy = piy - pospf[(i64)j * 2 + 1];                           \
      float attr = sqrtf((dx * dx + dy * dy) + 1e-12f);                 \
      int dc = deg2f[j];                                                \
      float invc = (dc > 0) ? 1.0f / (float)dc : 0.0f;                  \
      float w = attr * (invi + invc);                                   \
      if (w > best) { best = w; bc = cu; }                              \
      else if (w == best && cu < bc) bc = cu;                           \
    }                                                                   \
  }
  {
    int xx = i & GMSK, yy = i >> GSH;
    NB2(yy > 0, i - GWD)
    NB2(xx > 0, i - 1)
    NB2(xx < GMSK, i + 1)
    NB2(yy < GMSK, i + GWD)
  }
  if (mut) {
    int qx = p & GMSK, qy = p >> GSH;
    NB2(qy > 0, p - GWD)
    NB2(qx > 0, p - 1)
    NB2(qx < GMSK, p + 1)
    NB2(qy < GMSK, p + GWD)
  }
#undef NB2
  partner2[i] = (bc >= n) ? i : bc;
}

// ============ P: deterministic compaction of level-2 heads ============
__device__ __forceinline__ bool l2head(const int* __restrict__ c1,
                                       const int* __restrict__ partner2, int i, int n) {
  if (i >= n || c1[i] != i) return false;
  int p2 = partner2[i];
  bool mut2 = (p2 != i) && (partner2[p2] == i);
  return !(mut2 && p2 < i);
}

__global__ __launch_bounds__(256)
void kP_count(const int* __restrict__ c1, const int* __restrict__ partner2,
              int* __restrict__ blockCounts, int n) {
  int i = blockIdx.x * 256 + threadIdx.x;
  bool a = l2head(c1, partner2, i, n);
  u64 b = __ballot(a);
  __shared__ int wc4[4];
  int lane = threadIdx.x & 63, wv = threadIdx.x >> 6;
  if (lane == 0) wc4[wv] = __popcll(b);
  __syncthreads();
  if (threadIdx.x == 0) blockCounts[blockIdx.x] = wc4[0] + wc4[1] + wc4[2] + wc4[3];
}

__global__ __launch_bounds__(256)
void kP_scan(const int* __restrict__ blockCounts, int* __restrict__ blockOffsets,
             int* __restrict__ countBuf, int nblk) {
  __shared__ int tsum[256];
  __shared__ int toff[256];
  int t = threadIdx.x;
  int per = (nblk + 255) / 256;
  int base = t * per;
  int s = 0;
  for (int k = 0; k < per; ++k) { int q = base + k; if (q < nblk) s += blockCounts[q]; }
  tsum[t] = s;
  __syncthreads();
  if (t == 0) {
    int a = 0;
    for (int k = 0; k < 256; ++k) { toff[k] = a; a += tsum[k]; }
    *countBuf = a;
  }
  __syncthreads();
  int off = toff[t];
  for (int k = 0; k < per; ++k) {
    int q = base + k;
    if (q < nblk) { blockOffsets[q] = off; off += blockCounts[q]; }
  }
}

__global__ __launch_bounds__(256)
void kP_write(const int* __restrict__ c1, const int* __restrict__ partner2,
              const int* __restrict__ blockOffsets, int* __restrict__ L, int n) {
  int i = blockIdx.x * 256 + threadIdx.x;
  bool a = l2head(c1, partner2, i, n);
  u64 b = __ballot(a);
  int lane = threadIdx.x & 63, wv = threadIdx.x >> 6;
  __shared__ int woff[4];
  if (lane == 0) woff[wv] = __popcll(b);
  __syncthreads();
  int pre = 0;
  for (int k = 0; k < wv; ++k) pre += woff[k];
  int rank = __popcll(b & ((lane == 0) ? 0ull : ((1ull << lane) - 1ull)));
  if (a) L[blockOffsets[blockIdx.x] + pre + rank] = i;
}

// ============ E2: conv2 + pool2 + reduce — half-wave per cluster, lane = feature ============
__device__ __forceinline__ float rowdot16(const float* __restrict__ row, const float (&w)[16]) {
  float a = 0.f;
#pragma unroll
  for (int k = 0; k < 16; ++k) a += row[k] * w[k];
  return a;
}

__device__ __forceinline__ void gatherC(const int* __restrict__ c1,
                                        const float* __restrict__ xpf,
                                        int m, int cid, const float (&wc)[16],
                                        float& s, int& cnt) {
  int mx = m & GMSK, my = m >> GSH;
  if (my > 0)    { int j = m - GWD; if (c1[j] != cid) { ++cnt; s += rowdot16(xpf + (i64)j * 16, wc); } }
  if (mx > 0)    { int j = m - 1;   if (c1[j] != cid) { ++cnt; s += rowdot16(xpf + (i64)j * 16, wc); } }
  if (mx < GMSK) { int j = m + 1;   if (c1[j] != cid) { ++cnt; s += rowdot16(xpf + (i64)j * 16, wc); } }
  if (my < GMSK) { int j = m + GWD; if (c1[j] != cid) { ++cnt; s += rowdot16(xpf + (i64)j * 16, wc); } }
}

__global__ __launch_bounds__(256)
void kE2_conv2_reduce(const int* __restrict__ partner1, const int* __restrict__ c1,
                      const int* __restrict__ partner2, const float* __restrict__ xpf,
                      const float* __restrict__ W2, const float* __restrict__ W2r,
                      const float* __restrict__ b2,
                      const int* __restrict__ L, const int* __restrict__ countBuf,
                      float* __restrict__ partials) {
  int f = threadIdx.x & 31;       // feature owned by this lane
  int half = threadIdx.x >> 5;    // 0..7 cluster slot in block
  float wc[16], wr[16];
#pragma unroll
  for (int k = 0; k < 16; ++k) { wc[k] = W2[k * 32 + f]; wr[k] = W2r[k * 32 + f]; }
  float bf = b2[f];
  int count = *countBuf;

  float accf = 0.f, ccount = 0.f;
  for (int ci = blockIdx.x * 8 + half; ci < count; ci += gridDim.x * 8) {
    int h = L[ci];
    int pA = partner1[h];
    bool mA = (partner1[pA] == h);
    float sA = 0.f; int cntA = 0;
    gatherC(c1, xpf, h, h, wc, sA, cntA);
    if (mA) gatherC(c1, xpf, pA, h, wc, sA, cntA);
    float rA = rowdot16(xpf + (i64)h * 16, wr);
    float val = fmaxf(sA / (float)(cntA > 1 ? cntA : 1) + rA + bf, 0.0f);
    int p2 = partner2[h];
    bool mut2 = (p2 != h) && (partner2[p2] == h);
    if (mut2) {
      int pB = partner1[p2];
      bool mB = (partner1[pB] == p2);
      float sB = 0.f; int cntB = 0;
      gatherC(c1, xpf, p2, p2, wc, sB, cntB);
      if (mB) gatherC(c1, xpf, pB, p2, wc, sB, cntB);
      float rB = rowdot16(xpf + (i64)p2 * 16, wr);
      val = fmaxf(val, fmaxf(sB / (float)(cntB > 1 ? cntB : 1) + rB + bf, 0.0f));
    }
    accf += val;
    ccount += 1.f;
  }

  __shared__ float sm[8][33];
  sm[half][f] = accf;
  if (f == 0) sm[half][32] = ccount;
  __syncthreads();
  if (threadIdx.x < 33) {
    float v = 0.f;
#pragma unroll
    for (int s = 0; s < 8; ++s) v += sm[s][threadIdx.x];
    partials[(i64)threadIdx.x * NBE + blockIdx.x] = v;
  }
}

// ============ F: final reduce + MLP head ============
__global__ __launch_bounds__(256)
void k_final(const float* __restrict__ partials, int NB,
             const float* __restrict__ lin1w, const float* __restrict__ lin1b,
             const float* __restrict__ lin2w, const float* __restrict__ lin2b,
             float* __restrict__ out) {
  __shared__ float acc[33][4];
  __shared__ float tot[33];
  int t = threadIdx.x;
  int r = t >> 2, q = t & 3;
  int chunk = NB / 4;
  if (r < 33) {
    const float* pp = partials + (i64)r * NB + (i64)q * chunk;
    float a = 0.f;
    for (int b = 0; b < chunk; ++b) a += pp[b];
    acc[r][q] = a;
  }
  __syncthreads();
  if (t < 33) tot[t] = acc[t][0] + acc[t][1] + acc[t][2] + acc[t][3];
  __syncthreads();
  if (t == 0) {
    float cnt = tot[32];
    float pooled[32];
    for (int f = 0; f < 32; ++f) pooled[f] = tot[f] / cnt;
    float h[8];
    for (int j = 0; j < 8; ++j) {
      float a = 0.f;
      for (int k = 0; k < 32; ++k) a += pooled[k] * lin1w[k * 8 + j];
      a += lin1b[j];
      h[j] = a >= 0.f ? a : 0.1f * a;
    }
    for (int m = 0; m < 2; ++m) {
      float a = 0.f;
      for (int j = 0; j < 8; ++j) a += h[j] * lin2w[j * 2 + m];
      out[m] = a + lin2b[m];
    }
  }
}

extern "C" void kernel_launch(void* const* d_in, const int* in_sizes, int n_in,
                              void* d_out, int out_size, void* d_ws, size_t ws_size,
                              hipStream_t stream) {
  const float* x   = (const float*)d_in[0];
  const float* pos = (const float*)d_in[1];
  const float* W1  = (const float*)d_in[3];
  const float* W1r = (const float*)d_in[4];
  const float* b1  = (const float*)d_in[5];
  const float* W2  = (const float*)d_in[6];
  const float* W2r = (const float*)d_in[7];
  const float* b2  = (const float*)d_in[8];
  const float* l1w = (const float*)d_in[9];
  const float* l1b = (const float*)d_in[10];
  const float* l2w = (const float*)d_in[11];
  const float* l2b = (const float*)d_in[12];
  float* out = (float*)d_out;

  const int n = in_sizes[0] / 5;  // 1048576
  const int B = 256;
  const int gn = (n + B - 1) / B; // 4096

  // workspace: 16n + 2n floats + 5n ints + small  ≈ 96.5 MB
  float* base = (float*)d_ws;
  i64 off = 0;
  float* xpf      = base + off; off += (i64)16 * n;
  float* pospf    = base + off; off += (i64)2 * n;
  int*   partner1 = (int*)(base + off); off += n;
  int*   c1       = (int*)(base + off); off += n;
  int*   deg2f    = (int*)(base + off); off += n;
  int*   partner2 = (int*)(base + off); off += n;
  int*   L        = (int*)(base + off); off += n;
  int*   blkCnt   = (int*)(base + off); off += gn;
  int*   blkOff   = (int*)(base + off); off += gn;
  int*   countBuf = (int*)(base + off); off += 1;
  float* partials = base + off; off += (i64)33 * NBE;
  (void)ws_size; (void)n_in; (void)out_size;

  kA_match1<<<gn, B, 0, stream>>>(x, partner1, n);
  kB_pool1<<<gn, B, 0, stream>>>(x, pos, partner1, W1, W1r, b1, c1, xpf, pospf, n);
  kC_deg2<<<gn, B, 0, stream>>>(partner1, c1, deg2f, n);
  kD_match2<<<gn, B, 0, stream>>>(partner1, c1, pospf, deg2f, partner2, n);
  kP_count<<<gn, B, 0, stream>>>(c1, partner2, blkCnt, n);
  kP_scan<<<1, 256, 0, stream>>>(blkCnt, blkOff, countBuf, gn);
  kP_write<<<gn, B, 0, stream>>>(c1, partner2, blkOff, L, n);
  kE2_conv2_reduce<<<NBE, B, 0, stream>>>(partner1, c1, partner2, xpf, W2, W2r, b2,
                                          L, countBuf, partials);
  k_final<<<1, 256, 0, stream>>>(partials, NBE, l1w, l1b, l2w, l2b, out);
}

// Round 7
// 245.395 us; speedup vs baseline: 3.0270x; 3.0270x over previous
//
#include <hip/hip_runtime.h>
#include <math.h>

typedef long long i64;
typedef unsigned long long u64;

#define GWD 1024
#define GMSK 1023
#define GSH 10

__device__ __forceinline__ int deg_of(int m) {
  int xx = m & GMSK, yy = m >> GSH;
  return (xx > 0) + (xx < GMSK) + (yy > 0) + (yy < GMSK);
}

// ============ A: level-1 matching, fully static neighbor slots ============
__global__ __launch_bounds__(256)
void kA_match1(const float* __restrict__ x, int* __restrict__ partner1, int n) {
#pragma clang fp contract(off)
  int m = blockIdx.x * 256 + threadIdx.x;
  if (m >= n) return;
  int xx = m & GMSK, yy = m >> GSH;
  bool vW = xx > 0, vE = xx < GMSK, vN = yy > 0, vS = yy < GMSK;
  int cnt = (int)vW + (int)vE + (int)vN + (int)vS;
  float invi = 1.0f / (float)cnt;
  float xm0 = x[(i64)m * 5];
  float best = -INFINITY;
  int pr = n;
#define NB1(valid, J)                                                  \
  if (valid) {                                                         \
    int j = (J);                                                       \
    float a0 = x[(i64)j * 5];                                          \
    float w = fabsf(xm0 - a0) * (invi + 1.0f / (float)deg_of(j));      \
    if (w > best) { best = w; pr = j; }                                \
  }
  NB1(vN, m - GWD)
  NB1(vW, m - 1)
  NB1(vE, m + 1)
  NB1(vS, m + GWD)
#undef NB1
  partner1[m] = pr;
}

// ============ B: c1, pooled features (replicated), centroids (replicated) ============
__device__ __forceinline__ void conv1_static(const float* __restrict__ x, int m,
                                             const float* w1, const float* w1r,
                                             const float* b1, float (&out)[16]) {
  int xx = m & GMSK, yy = m >> GSH;
  bool vW = xx > 0, vE = xx < GMSK, vN = yy > 0, vS = yy < GMSK;
  int cnt = (int)vW + (int)vE + (int)vN + (int)vS;
  float s0 = 0.f, s1 = 0.f, s2 = 0.f, s3 = 0.f, s4 = 0.f;
#define ACC1(valid, J)                                     \
  if (valid) {                                             \
    const float* xj = x + (i64)(J) * 5;                    \
    s0 += xj[0]; s1 += xj[1]; s2 += xj[2];                 \
    s3 += xj[3]; s4 += xj[4];                              \
  }
  ACC1(vN, m - GWD)
  ACC1(vW, m - 1)
  ACC1(vE, m + 1)
  ACC1(vS, m + GWD)
#undef ACC1
  const float* xm = x + (i64)m * 5;
  float m0 = xm[0], m1 = xm[1], m2 = xm[2], m3 = xm[3], m4 = xm[4];
  float cf = (float)cnt;
#pragma unroll
  for (int f = 0; f < 16; ++f) {
    float a  = s0 * w1[f] + s1 * w1[16 + f] + s2 * w1[32 + f] + s3 * w1[48 + f] + s4 * w1[64 + f];
    float rt = m0 * w1r[f] + m1 * w1r[16 + f] + m2 * w1r[32 + f] + m3 * w1r[48 + f] + m4 * w1r[64 + f];
    out[f] = fmaxf(a / cf + rt + b1[f], 0.0f);
  }
}

__global__ __launch_bounds__(256)
void kB_pool1(const float* __restrict__ x, const float* __restrict__ pos,
              const int* __restrict__ partner1,
              const float* __restrict__ W1, const float* __restrict__ W1r,
              const float* __restrict__ b1,
              int* __restrict__ c1, float* __restrict__ xpf,
              float* __restrict__ pospf, int n) {
#pragma clang fp contract(off)
  __shared__ float w1s[80], w1rs[80], b1s[16];
  for (int t = threadIdx.x; t < 80; t += 256) { w1s[t] = W1[t]; w1rs[t] = W1r[t]; }
  if (threadIdx.x < 16) b1s[threadIdx.x] = b1[threadIdx.x];
  __syncthreads();
  int m = blockIdx.x * 256 + threadIdx.x;
  if (m >= n) return;
  int p = partner1[m];
  bool mut = (partner1[p] == m);
  c1[m] = mut ? min(m, p) : m;

  float px = pos[(i64)m * 2], py = pos[(i64)m * 2 + 1];
  if (mut) {
    px = (px + pos[(i64)p * 2]) * 0.5f;
    py = (py + pos[(i64)p * 2 + 1]) * 0.5f;
  }
  pospf[(i64)m * 2] = px;
  pospf[(i64)m * 2 + 1] = py;

  float v[16];
  conv1_static(x, m, w1s, w1rs, b1s, v);
  if (mut) {
    float u[16];
    conv1_static(x, p, w1s, w1rs, b1s, u);
#pragma unroll
    for (int f = 0; f < 16; ++f) v[f] = fmaxf(v[f], u[f]);
  }
#pragma unroll
  for (int f = 0; f < 16; ++f) xpf[(i64)m * 16 + f] = v[f];
}

// ============ C: coarse degree (replicated per node) ============
__device__ __forceinline__ int dcount(const int* __restrict__ c1, int q, int cq) {
  int xx = q & GMSK, yy = q >> GSH;
  int d = 0;
  if (yy > 0    && c1[q - GWD] != cq) ++d;
  if (xx > 0    && c1[q - 1]   != cq) ++d;
  if (xx < GMSK && c1[q + 1]   != cq) ++d;
  if (yy < GMSK && c1[q + GWD] != cq) ++d;
  return d;
}

__global__ __launch_bounds__(256)
void kC_deg2(const int* __restrict__ partner1, const int* __restrict__ c1,
             int* __restrict__ deg2f, int n) {
  int m = blockIdx.x * 256 + threadIdx.x;
  if (m >= n) return;
  int cm = c1[m];
  int p = partner1[m];
  bool mut = (partner1[p] == m);
  int d = dcount(c1, m, cm);
  if (mut) d += dcount(c1, p, cm);
  deg2f[m] = d;
}

// ============ D: level-2 matching (heads only), static 8 slots ============
__global__ __launch_bounds__(256)
void kD_match2(const int* __restrict__ partner1, const int* __restrict__ c1,
               const float* __restrict__ pospf, const int* __restrict__ deg2f,
               int* __restrict__ partner2, int n) {
#pragma clang fp contract(off)
  int i = blockIdx.x * 256 + threadIdx.x;
  if (i >= n) return;
  if (c1[i] != i) return;  // heads only
  int p = partner1[i];
  bool mut = (partner1[p] == i);
  float pix = pospf[(i64)i * 2], piy = pospf[(i64)i * 2 + 1];
  int di = deg2f[i];
  float invi = (di > 0) ? 1.0f / (float)di : 0.0f;
  float best = -INFINITY;
  int bc = n;
#define NB2(valid, J)                                                   \
  if (valid) {                                                          \
    int j = (J);                                                        \
    int cu = c1[j];                                                     \
    if (cu != i) {                                                      \
      float dx = pix - pospf[(i64)j * 2];                               \
      float dy = piy - pospf[(i64)j * 2 + 1];                           \
      float attr = sqrtf((dx * dx + dy * dy) + 1e-12f);                 \
      int dc = deg2f[j];                                                \
      float invc = (dc > 0) ? 1.0f / (float)dc : 0.0f;                  \
      float w = attr * (invi + invc);                                   \
      if (w > best) { best = w; bc = cu; }                              \
      else if (w == best && cu < bc) bc = cu;                           \
    }                                                                   \
  }
  {
    int xx = i & GMSK, yy = i >> GSH;
    NB2(yy > 0, i - GWD)
    NB2(xx > 0, i - 1)
    NB2(xx < GMSK, i + 1)
    NB2(yy < GMSK, i + GWD)
  }
  if (mut) {
    int qx = p & GMSK, qy = p >> GSH;
    NB2(qy > 0, p - GWD)
    NB2(qx > 0, p - 1)
    NB2(qx < GMSK, p + 1)
    NB2(qy < GMSK, p + GWD)
  }
#undef NB2
  partner2[i] = (bc >= n) ? i : bc;
}

// ============ P: deterministic compaction of level-2 heads ============
__device__ __forceinline__ bool l2head(const int* __restrict__ c1,
                                       const int* __restrict__ partner2, int i, int n) {
  if (i >= n || c1[i] != i) return false;
  int p2 = partner2[i];
  bool mut2 = (p2 != i) && (partner2[p2] == i);
  return !(mut2 && p2 < i);
}

__global__ __launch_bounds__(256)
void kP_count(const int* __restrict__ c1, const int* __restrict__ partner2,
              int* __restrict__ blockCounts, int n) {
  int i = blockIdx.x * 256 + threadIdx.x;
  bool a = l2head(c1, partner2, i, n);
  u64 b = __ballot(a);
  __shared__ int wc4[4];
  int lane = threadIdx.x & 63, wv = threadIdx.x >> 6;
  if (lane == 0) wc4[wv] = __popcll(b);
  __syncthreads();
  if (threadIdx.x == 0) blockCounts[blockIdx.x] = wc4[0] + wc4[1] + wc4[2] + wc4[3];
}

__global__ __launch_bounds__(256)
void kP_scan(const int* __restrict__ blockCounts, int* __restrict__ blockOffsets,
             int* __restrict__ countBuf, int nblk) {
  __shared__ int tsum[256];
  __shared__ int toff[256];
  int t = threadIdx.x;
  int per = (nblk + 255) / 256;
  int base = t * per;
  int s = 0;
  for (int k = 0; k < per; ++k) { int q = base + k; if (q < nblk) s += blockCounts[q]; }
  tsum[t] = s;
  __syncthreads();
  if (t == 0) {
    int a = 0;
    for (int k = 0; k < 256; ++k) { toff[k] = a; a += tsum[k]; }
    *countBuf = a;
  }
  __syncthreads();
  int off = toff[t];
  for (int k = 0; k < per; ++k) {
    int q = base + k;
    if (q < nblk) { blockOffsets[q] = off; off += blockCounts[q]; }
  }
}

__global__ __launch_bounds__(256)
void kP_write(const int* __restrict__ c1, const int* __restrict__ partner2,
              const int* __restrict__ blockOffsets, int* __restrict__ L, int n) {
  int i = blockIdx.x * 256 + threadIdx.x;
  bool a = l2head(c1, partner2, i, n);
  u64 b = __ballot(a);
  int lane = threadIdx.x & 63, wv = threadIdx.x >> 6;
  __shared__ int woff[4];
  if (lane == 0) woff[wv] = __popcll(b);
  __syncthreads();
  int pre = 0;
  for (int k = 0; k < wv; ++k) pre += woff[k];
  int rank = __popcll(b & ((lane == 0) ? 0ull : ((1ull << lane) - 1ull)));
  if (a) L[blockOffsets[blockIdx.x] + pre + rank] = i;
}

// ============ E3: conv2 + pool2 + block reduction over COMPACTED list ============
#define DECL16(P) \
  float P##0=0.f,P##1=0.f,P##2=0.f,P##3=0.f,P##4=0.f,P##5=0.f,P##6=0.f,P##7=0.f, \
        P##8=0.f,P##9=0.f,P##10=0.f,P##11=0.f,P##12=0.f,P##13=0.f,P##14=0.f,P##15=0.f

#define LOAD16(P, ptr) do { const float* _q=(ptr); \
  P##0=_q[0]; P##1=_q[1]; P##2=_q[2]; P##3=_q[3]; P##4=_q[4]; P##5=_q[5]; P##6=_q[6]; P##7=_q[7]; \
  P##8=_q[8]; P##9=_q[9]; P##10=_q[10]; P##11=_q[11]; P##12=_q[12]; P##13=_q[13]; P##14=_q[14]; P##15=_q[15]; } while(0)

#define ADD16(P, ptr) do { const float* _q=(ptr); \
  P##0+=_q[0]; P##1+=_q[1]; P##2+=_q[2]; P##3+=_q[3]; P##4+=_q[4]; P##5+=_q[5]; P##6+=_q[6]; P##7+=_q[7]; \
  P##8+=_q[8]; P##9+=_q[9]; P##10+=_q[10]; P##11+=_q[11]; P##12+=_q[12]; P##13+=_q[13]; P##14+=_q[14]; P##15+=_q[15]; } while(0)

#define DOTW(P, W, f) \
  (P##0*(W)[(f)] + P##1*(W)[32+(f)] + P##2*(W)[64+(f)] + P##3*(W)[96+(f)] + \
   P##4*(W)[128+(f)] + P##5*(W)[160+(f)] + P##6*(W)[192+(f)] + P##7*(W)[224+(f)] + \
   P##8*(W)[256+(f)] + P##9*(W)[288+(f)] + P##10*(W)[320+(f)] + P##11*(W)[352+(f)] + \
   P##12*(W)[384+(f)] + P##13*(W)[416+(f)] + P##14*(W)[448+(f)] + P##15*(W)[480+(f)])

#define GATHER_MEMBER(P, CNT, m, cid) do {                                     \
  int _m = (m); int _mx = _m & GMSK, _my = _m >> GSH;                           \
  if (_my > 0)    { int _j = _m - GWD; if (c1[_j] != (cid)) { ++CNT; ADD16(P, xpf + (i64)_j * 16); } } \
  if (_mx > 0)    { int _j = _m - 1;   if (c1[_j] != (cid)) { ++CNT; ADD16(P, xpf + (i64)_j * 16); } } \
  if (_mx < GMSK) { int _j = _m + 1;   if (c1[_j] != (cid)) { ++CNT; ADD16(P, xpf + (i64)_j * 16); } } \
  if (_my < GMSK) { int _j = _m + GWD; if (c1[_j] != (cid)) { ++CNT; ADD16(P, xpf + (i64)_j * 16); } } \
} while(0)

__global__ __launch_bounds__(256)
void kE3_conv2_reduce(const int* __restrict__ partner1, const int* __restrict__ c1,
                      const int* __restrict__ partner2, const float* __restrict__ xpf,
                      const float* __restrict__ W2, const float* __restrict__ W2r,
                      const float* __restrict__ b2,
                      const int* __restrict__ L, const int* __restrict__ countBuf,
                      float* __restrict__ partials) {
  int count = *countBuf;
  int t = blockIdx.x * 256 + threadIdx.x;
  bool active = t < count;
  bool mut2 = false;
  int h = 0, p2 = 0;

  DECL16(sA); DECL16(hA); int cntA = 0;
  DECL16(sB); DECL16(hB); int cntB = 0;
  if (active) {
    h = L[t];
    p2 = partner2[h];
    mut2 = (p2 != h) && (partner2[p2] == h);
    int pA = partner1[h];
    bool mA = (partner1[pA] == h);
    GATHER_MEMBER(sA, cntA, h, h);
    if (mA) GATHER_MEMBER(sA, cntA, pA, h);
    LOAD16(hA, xpf + (i64)h * 16);
    if (mut2) {
      int pB = partner1[p2];
      bool mB = (partner1[pB] == p2);
      GATHER_MEMBER(sB, cntB, p2, p2);
      if (mB) GATHER_MEMBER(sB, cntB, pB, p2);
      LOAD16(hB, xpf + (i64)p2 * 16);
    }
  }
  float cfA = (float)(cntA > 1 ? cntA : 1);
  float cfB = (float)(cntB > 1 ? cntB : 1);

  __shared__ float sm[4 * 33];
  int lane = threadIdx.x & 63, wv = threadIdx.x >> 6;

  for (int f = 0; f < 32; ++f) {  // f wave-uniform: weight reads are scalar loads
    float val = 0.f;
    if (active) {
      float a  = DOTW(sA, W2, f);
      float rt = DOTW(hA, W2r, f);
      val = fmaxf(a / cfA + rt + b2[f], 0.0f);
      if (mut2) {
        float ab  = DOTW(sB, W2, f);
        float rtb = DOTW(hB, W2r, f);
        val = fmaxf(val, fmaxf(ab / cfB + rtb + b2[f], 0.0f));
      }
    }
    for (int o = 32; o > 0; o >>= 1) val += __shfl_down(val, o, 64);
    if (lane == 0) sm[wv * 33 + f] = val;
  }
  {
    float v = active ? 1.f : 0.f;
    for (int o = 32; o > 0; o >>= 1) v += __shfl_down(v, o, 64);
    if (lane == 0) sm[wv * 33 + 32] = v;
  }
  __syncthreads();
  if (threadIdx.x < 33) {
    float v = sm[threadIdx.x] + sm[33 + threadIdx.x] + sm[66 + threadIdx.x] + sm[99 + threadIdx.x];
    partials[(i64)threadIdx.x * gridDim.x + blockIdx.x] = v;
  }
}

// ============ F1: parallel row reduction of partials[33][NB] ============
__global__ __launch_bounds__(256)
void kF1_rowsum(const float* __restrict__ partials, int NB, float* __restrict__ tot) {
  int r = blockIdx.x;  // 0..32
  const float* p = partials + (i64)r * NB;
  float a = 0.f;
  for (int k = threadIdx.x; k < NB; k += 256) a += p[k];
  __shared__ float sm[256];
  sm[threadIdx.x] = a;
  __syncthreads();
  for (int s = 128; s > 0; s >>= 1) {
    if (threadIdx.x < s) sm[threadIdx.x] += sm[threadIdx.x + s];
    __syncthreads();
  }
  if (threadIdx.x == 0) tot[r] = sm[0];
}

// ============ F2: tiny MLP head ============
__global__ __launch_bounds__(64)
void kF2_mlp(const float* __restrict__ tot,
             const float* __restrict__ lin1w, const float* __restrict__ lin1b,
             const float* __restrict__ lin2w, const float* __restrict__ lin2b,
             float* __restrict__ out) {
  if (threadIdx.x != 0) return;
  float cnt = tot[32];
  float pooled[32];
#pragma unroll
  for (int f = 0; f < 32; ++f) pooled[f] = tot[f] / cnt;
  float h[8];
#pragma unroll
  for (int j = 0; j < 8; ++j) {
    float a = 0.f;
#pragma unroll
    for (int k = 0; k < 32; ++k) a += pooled[k] * lin1w[k * 8 + j];
    a += lin1b[j];
    h[j] = a >= 0.f ? a : 0.1f * a;
  }
#pragma unroll
  for (int m = 0; m < 2; ++m) {
    float a = 0.f;
#pragma unroll
    for (int j = 0; j < 8; ++j) a += h[j] * lin2w[j * 2 + m];
    out[m] = a + lin2b[m];
  }
}

extern "C" void kernel_launch(void* const* d_in, const int* in_sizes, int n_in,
                              void* d_out, int out_size, void* d_ws, size_t ws_size,
                              hipStream_t stream) {
  const float* x   = (const float*)d_in[0];
  const float* pos = (const float*)d_in[1];
  const float* W1  = (const float*)d_in[3];
  const float* W1r = (const float*)d_in[4];
  const float* b1  = (const float*)d_in[5];
  const float* W2  = (const float*)d_in[6];
  const float* W2r = (const float*)d_in[7];
  const float* b2  = (const float*)d_in[8];
  const float* l1w = (const float*)d_in[9];
  const float* l1b = (const float*)d_in[10];
  const float* l2w = (const float*)d_in[11];
  const float* l2b = (const float*)d_in[12];
  float* out = (float*)d_out;

  const int n = in_sizes[0] / 5;  // 1048576
  const int B = 256;
  const int gn = (n + B - 1) / B; // 4096

  float* base = (float*)d_ws;
  i64 off = 0;
  float* xpf      = base + off; off += (i64)16 * n;
  float* pospf    = base + off; off += (i64)2 * n;
  int*   partner1 = (int*)(base + off); off += n;
  int*   c1       = (int*)(base + off); off += n;
  int*   deg2f    = (int*)(base + off); off += n;
  int*   partner2 = (int*)(base + off); off += n;
  int*   L        = (int*)(base + off); off += n;
  int*   blkCnt   = (int*)(base + off); off += gn;
  int*   blkOff   = (int*)(base + off); off += gn;
  int*   countBuf = (int*)(base + off); off += 1;
  float* partials = base + off; off += (i64)33 * gn;
  float* tot      = base + off; off += 33;
  (void)ws_size; (void)n_in; (void)out_size;

  kA_match1<<<gn, B, 0, stream>>>(x, partner1, n);
  kB_pool1<<<gn, B, 0, stream>>>(x, pos, partner1, W1, W1r, b1, c1, xpf, pospf, n);
  kC_deg2<<<gn, B, 0, stream>>>(partner1, c1, deg2f, n);
  kD_match2<<<gn, B, 0, stream>>>(partner1, c1, pospf, deg2f, partner2, n);
  kP_count<<<gn, B, 0, stream>>>(c1, partner2, blkCnt, n);
  kP_scan<<<1, 256, 0, stream>>>(blkCnt, blkOff, countBuf, gn);
  kP_write<<<gn, B, 0, stream>>>(c1, partner2, blkOff, L, n);
  kE3_conv2_reduce<<<gn, B, 0, stream>>>(partner1, c1, partner2, xpf, W2, W2r, b2,
                                         L, countBuf, partials);
  kF1_rowsum<<<33, 256, 0, stream>>>(partials, gn, tot);
  kF2_mlp<<<1, 64, 0, stream>>>(tot, l1w, l1b, l2w, l2b, out);
}

// Round 8
// 230.063 us; speedup vs baseline: 3.2288x; 1.0666x over previous
//
#include <hip/hip_runtime.h>
#include <math.h>

typedef long long i64;
typedef unsigned long long u64;

#define GWD 1024
#define GMSK 1023
#define GSH 10

__device__ __forceinline__ int deg_of(int m) {
  int xx = m & GMSK, yy = m >> GSH;
  return (xx > 0) + (xx < GMSK) + (yy > 0) + (yy < GMSK);
}

// ============ A: level-1 matching, fully static neighbor slots ============
__global__ __launch_bounds__(256)
void kA_match1(const float* __restrict__ x, int* __restrict__ partner1, int n) {
#pragma clang fp contract(off)
  int m = blockIdx.x * 256 + threadIdx.x;
  if (m >= n) return;
  int xx = m & GMSK, yy = m >> GSH;
  bool vW = xx > 0, vE = xx < GMSK, vN = yy > 0, vS = yy < GMSK;
  int cnt = (int)vW + (int)vE + (int)vN + (int)vS;
  float invi = 1.0f / (float)cnt;
  float xm0 = x[(i64)m * 5];
  float best = -INFINITY;
  int pr = n;
#define NB1(valid, J)                                                  \
  if (valid) {                                                         \
    int j = (J);                                                       \
    float a0 = x[(i64)j * 5];                                          \
    float w = fabsf(xm0 - a0) * (invi + 1.0f / (float)deg_of(j));      \
    if (w > best) { best = w; pr = j; }                                \
  }
  NB1(vN, m - GWD)
  NB1(vW, m - 1)
  NB1(vE, m + 1)
  NB1(vS, m + GWD)
#undef NB1
  partner1[m] = pr;
}

// ============ B: c1, pooled features (replicated), centroids (replicated) ============
__device__ __forceinline__ void conv1_static(const float* __restrict__ x, int m,
                                             const float* w1, const float* w1r,
                                             const float* b1, float (&out)[16]) {
  int xx = m & GMSK, yy = m >> GSH;
  bool vW = xx > 0, vE = xx < GMSK, vN = yy > 0, vS = yy < GMSK;
  int cnt = (int)vW + (int)vE + (int)vN + (int)vS;
  float s0 = 0.f, s1 = 0.f, s2 = 0.f, s3 = 0.f, s4 = 0.f;
#define ACC1(valid, J)                                     \
  if (valid) {                                             \
    const float* xj = x + (i64)(J) * 5;                    \
    s0 += xj[0]; s1 += xj[1]; s2 += xj[2];                 \
    s3 += xj[3]; s4 += xj[4];                              \
  }
  ACC1(vN, m - GWD)
  ACC1(vW, m - 1)
  ACC1(vE, m + 1)
  ACC1(vS, m + GWD)
#undef ACC1
  const float* xm = x + (i64)m * 5;
  float m0 = xm[0], m1 = xm[1], m2 = xm[2], m3 = xm[3], m4 = xm[4];
  float cf = (float)cnt;
#pragma unroll
  for (int f = 0; f < 16; ++f) {
    float a  = s0 * w1[f] + s1 * w1[16 + f] + s2 * w1[32 + f] + s3 * w1[48 + f] + s4 * w1[64 + f];
    float rt = m0 * w1r[f] + m1 * w1r[16 + f] + m2 * w1r[32 + f] + m3 * w1r[48 + f] + m4 * w1r[64 + f];
    out[f] = fmaxf(a / cf + rt + b1[f], 0.0f);
  }
}

__global__ __launch_bounds__(256)
void kB_pool1(const float* __restrict__ x, const float* __restrict__ pos,
              const int* __restrict__ partner1,
              const float* __restrict__ W1, const float* __restrict__ W1r,
              const float* __restrict__ b1,
              int* __restrict__ c1, float* __restrict__ xpf,
              float* __restrict__ pospf, int n) {
#pragma clang fp contract(off)
  __shared__ float w1s[80], w1rs[80], b1s[16];
  for (int t = threadIdx.x; t < 80; t += 256) { w1s[t] = W1[t]; w1rs[t] = W1r[t]; }
  if (threadIdx.x < 16) b1s[threadIdx.x] = b1[threadIdx.x];
  __syncthreads();
  int m = blockIdx.x * 256 + threadIdx.x;
  if (m >= n) return;
  int p = partner1[m];
  bool mut = (partner1[p] == m);
  c1[m] = mut ? min(m, p) : m;

  float px = pos[(i64)m * 2], py = pos[(i64)m * 2 + 1];
  if (mut) {
    px = (px + pos[(i64)p * 2]) * 0.5f;
    py = (py + pos[(i64)p * 2 + 1]) * 0.5f;
  }
  pospf[(i64)m * 2] = px;
  pospf[(i64)m * 2 + 1] = py;

  float v[16];
  conv1_static(x, m, w1s, w1rs, b1s, v);
  if (mut) {
    float u[16];
    conv1_static(x, p, w1s, w1rs, b1s, u);
#pragma unroll
    for (int f = 0; f < 16; ++f) v[f] = fmaxf(v[f], u[f]);
  }
#pragma unroll
  for (int f = 0; f < 16; ++f) xpf[(i64)m * 16 + f] = v[f];
}

// ============ C: coarse degree (replicated per node) ============
__device__ __forceinline__ int dcount(const int* __restrict__ c1, int q, int cq) {
  int xx = q & GMSK, yy = q >> GSH;
  int d = 0;
  if (yy > 0    && c1[q - GWD] != cq) ++d;
  if (xx > 0    && c1[q - 1]   != cq) ++d;
  if (xx < GMSK && c1[q + 1]   != cq) ++d;
  if (yy < GMSK && c1[q + GWD] != cq) ++d;
  return d;
}

__global__ __launch_bounds__(256)
void kC_deg2(const int* __restrict__ partner1, const int* __restrict__ c1,
             int* __restrict__ deg2f, int n) {
  int m = blockIdx.x * 256 + threadIdx.x;
  if (m >= n) return;
  int cm = c1[m];
  int p = partner1[m];
  bool mut = (partner1[p] == m);
  int d = dcount(c1, m, cm);
  if (mut) d += dcount(c1, p, cm);
  deg2f[m] = d;
}

// ============ D: level-2 matching (heads only), static 8 slots ============
__global__ __launch_bounds__(256)
void kD_match2(const int* __restrict__ partner1, const int* __restrict__ c1,
               const float* __restrict__ pospf, const int* __restrict__ deg2f,
               int* __restrict__ partner2, int n) {
#pragma clang fp contract(off)
  int i = blockIdx.x * 256 + threadIdx.x;
  if (i >= n) return;
  if (c1[i] != i) return;  // heads only
  int p = partner1[i];
  bool mut = (partner1[p] == i);
  float pix = pospf[(i64)i * 2], piy = pospf[(i64)i * 2 + 1];
  int di = deg2f[i];
  float invi = (di > 0) ? 1.0f / (float)di : 0.0f;
  float best = -INFINITY;
  int bc = n;
#define NB2(valid, J)                                                   \
  if (valid) {                                                          \
    int j = (J);                                                        \
    int cu = c1[j];                                                     \
    if (cu != i) {                                                      \
      float dx = pix - pospf[(i64)j * 2];                               \
      float dy = piy - pospf[(i64)j * 2 + 1];                           \
      float attr = sqrtf((dx * dx + dy * dy) + 1e-12f);                 \
      int dc = deg2f[j];                                                \
      float invc = (dc > 0) ? 1.0f / (float)dc : 0.0f;                  \
      float w = attr * (invi + invc);                                   \
      if (w > best) { best = w; bc = cu; }                              \
      else if (w == best && cu < bc) bc = cu;                           \
    }                                                                   \
  }
  {
    int xx = i & GMSK, yy = i >> GSH;
    NB2(yy > 0, i - GWD)
    NB2(xx > 0, i - 1)
    NB2(xx < GMSK, i + 1)
    NB2(yy < GMSK, i + GWD)
  }
  if (mut) {
    int qx = p & GMSK, qy = p >> GSH;
    NB2(qy > 0, p - GWD)
    NB2(qx > 0, p - 1)
    NB2(qx < GMSK, p + 1)
    NB2(qy < GMSK, p + GWD)
  }
#undef NB2
  partner2[i] = (bc >= n) ? i : bc;
}

// ============ P: deterministic compaction of level-2 heads ============
__device__ __forceinline__ bool l2head(const int* __restrict__ c1,
                                       const int* __restrict__ partner2, int i, int n) {
  if (i >= n || c1[i] != i) return false;
  int p2 = partner2[i];
  bool mut2 = (p2 != i) && (partner2[p2] == i);
  return !(mut2 && p2 < i);
}

__global__ __launch_bounds__(256)
void kP_count(const int* __restrict__ c1, const int* __restrict__ partner2,
              int* __restrict__ blockCounts, int n) {
  int i = blockIdx.x * 256 + threadIdx.x;
  bool a = l2head(c1, partner2, i, n);
  u64 b = __ballot(a);
  __shared__ int wc4[4];
  int lane = threadIdx.x & 63, wv = threadIdx.x >> 6;
  if (lane == 0) wc4[wv] = __popcll(b);
  __syncthreads();
  if (threadIdx.x == 0) blockCounts[blockIdx.x] = wc4[0] + wc4[1] + wc4[2] + wc4[3];
}

__global__ __launch_bounds__(256)
void kP_scan(const int* __restrict__ blockCounts, int* __restrict__ blockOffsets,
             int* __restrict__ countBuf, int nblk) {
  __shared__ int tsum[256];
  __shared__ int toff[256];
  int t = threadIdx.x;
  int per = (nblk + 255) / 256;
  int base = t * per;
  int s = 0;
  for (int k = 0; k < per; ++k) { int q = base + k; if (q < nblk) s += blockCounts[q]; }
  tsum[t] = s;
  __syncthreads();
  if (t == 0) {
    int a = 0;
    for (int k = 0; k < 256; ++k) { toff[k] = a; a += tsum[k]; }
    *countBuf = a;
  }
  __syncthreads();
  int off = toff[t];
  for (int k = 0; k < per; ++k) {
    int q = base + k;
    if (q < nblk) { blockOffsets[q] = off; off += blockCounts[q]; }
  }
}

__global__ __launch_bounds__(256)
void kP_write(const int* __restrict__ c1, const int* __restrict__ partner2,
              const int* __restrict__ blockOffsets, int* __restrict__ L, int n) {
  int i = blockIdx.x * 256 + threadIdx.x;
  bool a = l2head(c1, partner2, i, n);
  u64 b = __ballot(a);
  int lane = threadIdx.x & 63, wv = threadIdx.x >> 6;
  __shared__ int woff[4];
  if (lane == 0) woff[wv] = __popcll(b);
  __syncthreads();
  int pre = 0;
  for (int k = 0; k < wv; ++k) pre += woff[k];
  int rank = __popcll(b & ((lane == 0) ? 0ull : ((1ull << lane) - 1ull)));
  if (a) L[blockOffsets[blockIdx.x] + pre + rank] = i;
}

// ============ E4: conv2 + pool2 — 2 lanes per L2 cluster (even: member A, odd: member B) ============
#define DECL16(P) \
  float P##0=0.f,P##1=0.f,P##2=0.f,P##3=0.f,P##4=0.f,P##5=0.f,P##6=0.f,P##7=0.f, \
        P##8=0.f,P##9=0.f,P##10=0.f,P##11=0.f,P##12=0.f,P##13=0.f,P##14=0.f,P##15=0.f

#define LOAD16(P, ptr) do { const float* _q=(ptr); \
  P##0=_q[0]; P##1=_q[1]; P##2=_q[2]; P##3=_q[3]; P##4=_q[4]; P##5=_q[5]; P##6=_q[6]; P##7=_q[7]; \
  P##8=_q[8]; P##9=_q[9]; P##10=_q[10]; P##11=_q[11]; P##12=_q[12]; P##13=_q[13]; P##14=_q[14]; P##15=_q[15]; } while(0)

#define ADD16(P, ptr) do { const float* _q=(ptr); \
  P##0+=_q[0]; P##1+=_q[1]; P##2+=_q[2]; P##3+=_q[3]; P##4+=_q[4]; P##5+=_q[5]; P##6+=_q[6]; P##7+=_q[7]; \
  P##8+=_q[8]; P##9+=_q[9]; P##10+=_q[10]; P##11+=_q[11]; P##12+=_q[12]; P##13+=_q[13]; P##14+=_q[14]; P##15+=_q[15]; } while(0)

#define DOTW(P, W, f) \
  (P##0*(W)[(f)] + P##1*(W)[32+(f)] + P##2*(W)[64+(f)] + P##3*(W)[96+(f)] + \
   P##4*(W)[128+(f)] + P##5*(W)[160+(f)] + P##6*(W)[192+(f)] + P##7*(W)[224+(f)] + \
   P##8*(W)[256+(f)] + P##9*(W)[288+(f)] + P##10*(W)[320+(f)] + P##11*(W)[352+(f)] + \
   P##12*(W)[384+(f)] + P##13*(W)[416+(f)] + P##14*(W)[448+(f)] + P##15*(W)[480+(f)])

#define GATHER_MEMBER(P, CNT, m, cid) do {                                     \
  int _m = (m); int _mx = _m & GMSK, _my = _m >> GSH;                           \
  if (_my > 0)    { int _j = _m - GWD; if (c1[_j] != (cid)) { ++CNT; ADD16(P, xpf + (i64)_j * 16); } } \
  if (_mx > 0)    { int _j = _m - 1;   if (c1[_j] != (cid)) { ++CNT; ADD16(P, xpf + (i64)_j * 16); } } \
  if (_mx < GMSK) { int _j = _m + 1;   if (c1[_j] != (cid)) { ++CNT; ADD16(P, xpf + (i64)_j * 16); } } \
  if (_my < GMSK) { int _j = _m + GWD; if (c1[_j] != (cid)) { ++CNT; ADD16(P, xpf + (i64)_j * 16); } } \
} while(0)

__global__ __launch_bounds__(256)
void kE4_conv2_reduce(const int* __restrict__ partner1, const int* __restrict__ c1,
                      const int* __restrict__ partner2, const float* __restrict__ xpf,
                      const float* __restrict__ W2, const float* __restrict__ W2r,
                      const float* __restrict__ b2,
                      const int* __restrict__ L, const int* __restrict__ countBuf,
                      float* __restrict__ partials) {
  int count = *countBuf;
  // whole-block early exit (must still zero our partials column)
  if ((i64)blockIdx.x * 128 >= (i64)count) {
    if (threadIdx.x < 33) partials[(i64)threadIdx.x * gridDim.x + blockIdx.x] = 0.f;
    return;
  }
  int gt = blockIdx.x * 256 + threadIdx.x;
  int pi = gt >> 1;       // cluster index
  int which = gt & 1;     // 0 = member A (head h), 1 = member B (p2, if mutual)
  bool active = pi < count;
  bool doconv = false;
  DECL16(s); DECL16(hh); int cnt = 0;
  if (active) {
    int h = L[pi];
    int p2 = partner2[h];
    bool mut2 = (p2 != h) && (partner2[p2] == h);
    int myhead = which ? p2 : h;
    doconv = (which == 0) || mut2;
    if (doconv) {
      int pm = partner1[myhead];
      bool mm = (partner1[pm] == myhead);
      GATHER_MEMBER(s, cnt, myhead, myhead);
      if (mm) GATHER_MEMBER(s, cnt, pm, myhead);
      LOAD16(hh, xpf + (i64)myhead * 16);
    }
  }
  float cf = (float)(cnt > 1 ? cnt : 1);

  __shared__ float sm[4 * 33];
  int lane = threadIdx.x & 63, wv = threadIdx.x >> 6;

  for (int f = 0; f < 32; ++f) {  // f wave-uniform: weight reads are scalar loads
    float val = 0.f;
    if (doconv) {
      float a  = DOTW(s, W2, f);
      float rt = DOTW(hh, W2r, f);
      val = fmaxf(a / cf + rt + b2[f], 0.0f);  // relu >= 0, so 0 is identity for pool-max
    }
    float pmx = fmaxf(val, __shfl_xor(val, 1, 64));   // max over the lane pair = pool2 max
    float contrib = (active && which == 0) ? pmx : 0.f;
    for (int o = 32; o > 0; o >>= 1) contrib += __shfl_down(contrib, o, 64);
    if (lane == 0) sm[wv * 33 + f] = contrib;
  }
  {
    float v = (active && which == 0) ? 1.f : 0.f;
    for (int o = 32; o > 0; o >>= 1) v += __shfl_down(v, o, 64);
    if (lane == 0) sm[wv * 33 + 32] = v;
  }
  __syncthreads();
  if (threadIdx.x < 33) {
    float v = sm[threadIdx.x] + sm[33 + threadIdx.x] + sm[66 + threadIdx.x] + sm[99 + threadIdx.x];
    partials[(i64)threadIdx.x * gridDim.x + blockIdx.x] = v;
  }
}

// ============ F1: parallel row reduction of partials[33][NB] ============
__global__ __launch_bounds__(256)
void kF1_rowsum(const float* __restrict__ partials, int NB, float* __restrict__ tot) {
  int r = blockIdx.x;  // 0..32
  const float* p = partials + (i64)r * NB;
  float a = 0.f;
  for (int k = threadIdx.x; k < NB; k += 256) a += p[k];
  __shared__ float sm[256];
  sm[threadIdx.x] = a;
  __syncthreads();
  for (int s = 128; s > 0; s >>= 1) {
    if (threadIdx.x < s) sm[threadIdx.x] += sm[threadIdx.x + s];
    __syncthreads();
  }
  if (threadIdx.x == 0) tot[r] = sm[0];
}

// ============ F2: tiny MLP head ============
__global__ __launch_bounds__(64)
void kF2_mlp(const float* __restrict__ tot,
             const float* __restrict__ lin1w, const float* __restrict__ lin1b,
             const float* __restrict__ lin2w, const float* __restrict__ lin2b,
             float* __restrict__ out) {
  if (threadIdx.x != 0) return;
  float cnt = tot[32];
  float pooled[32];
#pragma unroll
  for (int f = 0; f < 32; ++f) pooled[f] = tot[f] / cnt;
  float h[8];
#pragma unroll
  for (int j = 0; j < 8; ++j) {
    float a = 0.f;
#pragma unroll
    for (int k = 0; k < 32; ++k) a += pooled[k] * lin1w[k * 8 + j];
    a += lin1b[j];
    h[j] = a >= 0.f ? a : 0.1f * a;
  }
#pragma unroll
  for (int m = 0; m < 2; ++m) {
    float a = 0.f;
#pragma unroll
    for (int j = 0; j < 8; ++j) a += h[j] * lin2w[j * 2 + m];
    out[m] = a + lin2b[m];
  }
}

extern "C" void kernel_launch(void* const* d_in, const int* in_sizes, int n_in,
                              void* d_out, int out_size, void* d_ws, size_t ws_size,
                              hipStream_t stream) {
  const float* x   = (const float*)d_in[0];
  const float* pos = (const float*)d_in[1];
  const float* W1  = (const float*)d_in[3];
  const float* W1r = (const float*)d_in[4];
  const float* b1  = (const float*)d_in[5];
  const float* W2  = (const float*)d_in[6];
  const float* W2r = (const float*)d_in[7];
  const float* b2  = (const float*)d_in[8];
  const float* l1w = (const float*)d_in[9];
  const float* l1b = (const float*)d_in[10];
  const float* l2w = (const float*)d_in[11];
  const float* l2b = (const float*)d_in[12];
  float* out = (float*)d_out;

  const int n = in_sizes[0] / 5;  // 1048576
  const int B = 256;
  const int gn = (n + B - 1) / B; // 4096
  const int ge = 2 * gn;          // kE4 grid: 2 lanes per cluster, count <= n

  float* base = (float*)d_ws;
  i64 off = 0;
  float* xpf      = base + off; off += (i64)16 * n;
  float* pospf    = base + off; off += (i64)2 * n;
  int*   partner1 = (int*)(base + off); off += n;
  int*   c1       = (int*)(base + off); off += n;
  int*   deg2f    = (int*)(base + off); off += n;
  int*   partner2 = (int*)(base + off); off += n;
  int*   L        = (int*)(base + off); off += n;
  int*   blkCnt   = (int*)(base + off); off += gn;
  int*   blkOff   = (int*)(base + off); off += gn;
  int*   countBuf = (int*)(base + off); off += 1;
  float* partials = base + off; off += (i64)33 * ge;
  float* tot      = base + off; off += 33;
  (void)ws_size; (void)n_in; (void)out_size;

  kA_match1<<<gn, B, 0, stream>>>(x, partner1, n);
  kB_pool1<<<gn, B, 0, stream>>>(x, pos, partner1, W1, W1r, b1, c1, xpf, pospf, n);
  kC_deg2<<<gn, B, 0, stream>>>(partner1, c1, deg2f, n);
  kD_match2<<<gn, B, 0, stream>>>(partner1, c1, pospf, deg2f, partner2, n);
  kP_count<<<gn, B, 0, stream>>>(c1, partner2, blkCnt, n);
  kP_scan<<<1, 256, 0, stream>>>(blkCnt, blkOff, countBuf, gn);
  kP_write<<<gn, B, 0, stream>>>(c1, partner2, blkOff, L, n);
  kE4_conv2_reduce<<<ge, B, 0, stream>>>(partner1, c1, partner2, xpf, W2, W2r, b2,
                                         L, countBuf, partials);
  kF1_rowsum<<<33, 256, 0, stream>>>(partials, ge, tot);
  kF2_mlp<<<1, 64, 0, stream>>>(tot, l1w, l1b, l2w, l2b, out);
}